// Round 1
// baseline (226.926 us; speedup 1.0000x reference)
//
#include <hip/hip_runtime.h>

// SNN IF scan, T=4. Memory-bound: 134 MB in + 134 MB out (~43 us floor at
// copy rate). History: serialized loads (R0/R2/R5, VGPR<=32) = ~82 us;
// R4 16-deep nt batch = ~70 us; R6 32-deep u-major batch = ~62 us kernel
// (223.5 us bench incl. ~161 us harness fills).
//
// R7 theory: R6 is phase-convoyed — all waves lockstep {32-load burst ->
// consume/store burst -> MLP drains to 0}, x2 rounds. Read queues empty
// during store bursts; full drain between rounds. Fix: persistent-shaped
// pipeline. grid=512 (exactly 2 blocks/CU resident), per-thread work = 4
// batches x (4 u-steps x 4 t) loads, DOUBLE-BUFFERED: batch b+1's 16 loads
// are in flight while batch b is consumed/stored. Reads+writes co-resident
// continuously; MLP never drains until the tail. Same 128 data VGPRs as R6
// -> same 2 waves/SIMD; structure is the only variable.
// sched_barrier(0) pins each phase (R2/R5: unpinned batches get silently
// re-serialized — VGPR_Count >= ~130 verifies the buffers survived).

#define T_STEPS 4
#define BATCH 4    // u-steps per batch
#define NBATCH 4   // batches per thread
#define BLOCK 256

typedef float vfloat4 __attribute__((ext_vector_type(4)));

__global__ __launch_bounds__(256) void IF_18622978195596_kernel(
    const vfloat4* __restrict__ x, const float* __restrict__ thresh_p,
    vfloat4* __restrict__ out, int n4) {
    // n4 = 2^21 divides exactly by BLOCK*BATCH*NBATCH = 4096; no guards.
    const size_t base =
        (size_t)blockIdx.x * (BLOCK * BATCH * NBATCH) + threadIdx.x;
    const float th = *thresh_p;

    // Two named buffers (static indexing only — runtime-indexed ext_vector
    // arrays go to scratch).
    vfloat4 A[BATCH][T_STEPS];
    vfloat4 B[BATCH][T_STEPS];

#define LOADB(BUF, b)                                                        \
    _Pragma("unroll")                                                        \
    for (int u = 0; u < BATCH; ++u) {                                        \
        const size_t i = base + (size_t)((b) * BATCH + u) * BLOCK;           \
        _Pragma("unroll")                                                    \
        for (int t = 0; t < T_STEPS; ++t)                                    \
            BUF[u][t] = __builtin_nontemporal_load(&x[(size_t)t * n4 + i]);  \
    }

    // Consume in the same u-major/t-inner order as issue -> progressive
    // vmcnt drain; each group's stores overlap the next batch's in-flight
    // loads.
#define CONSUME(BUF, b)                                                      \
    _Pragma("unroll")                                                        \
    for (int u = 0; u < BATCH; ++u) {                                        \
        const size_t i = base + (size_t)((b) * BATCH + u) * BLOCK;           \
        vfloat4 mem = {0.5f * th, 0.5f * th, 0.5f * th, 0.5f * th};          \
        _Pragma("unroll")                                                    \
        for (int t = 0; t < T_STEPS; ++t) {                                  \
            mem += BUF[u][t];                                                \
            vfloat4 s;                                                       \
            s.x = (mem.x >= th) ? th : 0.0f;                                 \
            s.y = (mem.y >= th) ? th : 0.0f;                                 \
            s.z = (mem.z >= th) ? th : 0.0f;                                 \
            s.w = (mem.w >= th) ? th : 0.0f;                                 \
            mem -= s;                                                        \
            __builtin_nontemporal_store(s, &out[(size_t)t * n4 + i]);        \
        }                                                                    \
    }

    // Pipeline: prologue fills both buffers, then consume(b) overlaps
    // load(b+2)'s issue; every consume runs with >=16 loads in flight
    // except the final tail.
    LOADB(A, 0);
    __builtin_amdgcn_sched_barrier(0);
    LOADB(B, 1);
    __builtin_amdgcn_sched_barrier(0);
    CONSUME(A, 0);
    __builtin_amdgcn_sched_barrier(0);
    LOADB(A, 2);
    __builtin_amdgcn_sched_barrier(0);
    CONSUME(B, 1);
    __builtin_amdgcn_sched_barrier(0);
    LOADB(B, 3);
    __builtin_amdgcn_sched_barrier(0);
    CONSUME(A, 2);
    __builtin_amdgcn_sched_barrier(0);
    CONSUME(B, 3);

#undef LOADB
#undef CONSUME
}

extern "C" void kernel_launch(void* const* d_in, const int* in_sizes, int n_in,
                              void* d_out, int out_size, void* d_ws,
                              size_t ws_size, hipStream_t stream) {
    const float* x = (const float*)d_in[0];
    const float* thresh = (const float*)d_in[1];
    float* out = (float*)d_out;

    int total = in_sizes[0];        // 33,554,432 floats
    int n_per_t = total / T_STEPS;  // 8,388,608 neurons
    int n4 = n_per_t / 4;           // 2,097,152 vfloat4 per timestep

    int per_block = BLOCK * BATCH * NBATCH;  // 4096 vfloat4 per block per t
    int grid = n4 / per_block;               // 512 blocks = 2/CU, resident
    IF_18622978195596_kernel<<<grid, BLOCK, 0, stream>>>(
        (const vfloat4*)x, thresh, (vfloat4*)out, n4);
}

// Round 2
// 224.284 us; speedup vs baseline: 1.0118x; 1.0118x over previous
//
#include <hip/hip_runtime.h>

// SNN IF scan, T=4. Memory-bound: 134 MB in + 134 MB out (~43 us floor at
// copy rate). Ladder: serialized loads = ~82 us; R4 16-deep burst = ~70;
// R6 32-deep burst (grid 1024, ~12 waves/CU) = ~62; R7 32-deep continuous
// pipeline but grid 512 (8 waves/CU) = ~64.6 — continuity gain canceled by
// TLP loss.
//
// R8 theory: binder = sustained outstanding vmem ops per CU = waves/CU x
// per-wave depth, integrated over time (drains waste queue slots). Depth
// and waves trade off through VGPR: 32-deep needs ~170 VGPR (3 waves/SIMD),
// 16-deep fits <=128 (4 waves/SIMD). Unexplored corner: 16-deep AND
// continuous AND 4 waves/SIMD. Double buffer 8+8 loads (BATCH=2, NBATCH=4),
// __launch_bounds__(256,4) forces VGPR<=128, grid=1024 = 4 blocks/CU = 16
// waves/CU. Steady state: every wave always has 8-16 vmem ops in flight,
// no drain until tail.
// sched_barrier(0) pins each phase (R2/R5 lesson: unpinned batches get
// silently re-serialized — VGPR_Count around ~100-128, not <70, verifies
// the buffers survived; VGPR=128 with scratch>0 means the cap backfired).

#define T_STEPS 4
#define BATCH 2    // u-steps per batch (8 loads per buffer)
#define NBATCH 4   // batches per thread
#define BLOCK 256

typedef float vfloat4 __attribute__((ext_vector_type(4)));

__global__ __launch_bounds__(256, 4) void IF_18622978195596_kernel(
    const vfloat4* __restrict__ x, const float* __restrict__ thresh_p,
    vfloat4* __restrict__ out, int n4) {
    // n4 = 2^21 divides exactly by BLOCK*BATCH*NBATCH = 2048; no guards.
    const size_t base =
        (size_t)blockIdx.x * (BLOCK * BATCH * NBATCH) + threadIdx.x;
    const float th = *thresh_p;

    // Two named buffers (static indexing only — runtime-indexed ext_vector
    // arrays go to scratch, rule #20).
    vfloat4 A[BATCH][T_STEPS];
    vfloat4 B[BATCH][T_STEPS];

#define LOADB(BUF, b)                                                        \
    _Pragma("unroll")                                                        \
    for (int u = 0; u < BATCH; ++u) {                                        \
        const size_t i = base + (size_t)((b) * BATCH + u) * BLOCK;           \
        _Pragma("unroll")                                                    \
        for (int t = 0; t < T_STEPS; ++t)                                    \
            BUF[u][t] = __builtin_nontemporal_load(&x[(size_t)t * n4 + i]);  \
    }

    // Consume in issue order -> progressive vmcnt drain; stores overlap the
    // next batch's in-flight loads.
#define CONSUME(BUF, b)                                                      \
    _Pragma("unroll")                                                        \
    for (int u = 0; u < BATCH; ++u) {                                        \
        const size_t i = base + (size_t)((b) * BATCH + u) * BLOCK;           \
        vfloat4 mem = {0.5f * th, 0.5f * th, 0.5f * th, 0.5f * th};          \
        _Pragma("unroll")                                                    \
        for (int t = 0; t < T_STEPS; ++t) {                                  \
            mem += BUF[u][t];                                                \
            vfloat4 s;                                                       \
            s.x = (mem.x >= th) ? th : 0.0f;                                 \
            s.y = (mem.y >= th) ? th : 0.0f;                                 \
            s.z = (mem.z >= th) ? th : 0.0f;                                 \
            s.w = (mem.w >= th) ? th : 0.0f;                                 \
            mem -= s;                                                        \
            __builtin_nontemporal_store(s, &out[(size_t)t * n4 + i]);        \
        }                                                                    \
    }

    // Pipeline: prologue fills both buffers; thereafter each consume runs
    // with the other buffer's 8 loads in flight. No drain until the tail.
    LOADB(A, 0);
    __builtin_amdgcn_sched_barrier(0);
    LOADB(B, 1);
    __builtin_amdgcn_sched_barrier(0);
    CONSUME(A, 0);
    __builtin_amdgcn_sched_barrier(0);
    LOADB(A, 2);
    __builtin_amdgcn_sched_barrier(0);
    CONSUME(B, 1);
    __builtin_amdgcn_sched_barrier(0);
    LOADB(B, 3);
    __builtin_amdgcn_sched_barrier(0);
    CONSUME(A, 2);
    __builtin_amdgcn_sched_barrier(0);
    CONSUME(B, 3);

#undef LOADB
#undef CONSUME
}

extern "C" void kernel_launch(void* const* d_in, const int* in_sizes, int n_in,
                              void* d_out, int out_size, void* d_ws,
                              size_t ws_size, hipStream_t stream) {
    const float* x = (const float*)d_in[0];
    const float* thresh = (const float*)d_in[1];
    float* out = (float*)d_out;

    int total = in_sizes[0];        // 33,554,432 floats
    int n_per_t = total / T_STEPS;  // 8,388,608 neurons
    int n4 = n_per_t / 4;           // 2,097,152 vfloat4 per timestep

    int per_block = BLOCK * BATCH * NBATCH;  // 2048 vfloat4 per block per t
    int grid = n4 / per_block;               // 1024 blocks = 4/CU
    IF_18622978195596_kernel<<<grid, BLOCK, 0, stream>>>(
        (const vfloat4*)x, thresh, (vfloat4*)out, n4);
}

// Round 3
// 223.590 us; speedup vs baseline: 1.0149x; 1.0031x over previous
//
#include <hip/hip_runtime.h>

// SNN IF scan, T=4. Memory-bound: 134 MB in + 134 MB out (~43 us floor at
// copy rate). Ladder: serialized loads = ~82 us; 16-deep burst = ~70;
// R6 32-deep u-major burst = ~62; R7 continuous/8 waves = ~64.6;
// R8 16-deep continuous/16 waves = ~62. Three schedule shapes tie at ~62
// -> queue occupancy saturated; something else caps us at 4.3 TB/s vs
// 6.3 copy.
//
// R9 theory: plane stride is EXACTLY 32 MiB (n4*16B, power of two). HBM
// channel interleave uses low addr bits -> for fixed i, all 4 t-planes map
// to the SAME channel, different rows. R6's t-inner issue order sends 4
// consecutive row-conflicting requests to one channel per i, for loads AND
// stores: per-channel row thrash that queue depth only makes worse.
// Fix: plane-major issue. Loads t-outer (8 consecutive instrs = 8KB
// contiguous in one plane before hopping). Compute overwrites xv[u][t]
// in place with the spike (zero extra VGPR). Stores t-outer burst.
// Mirrors R6 otherwise (UNROLL=8, grid=1024) -> issue order is the
// isolated variable. sched_barrier(0) pins each plane group.

#define T_STEPS 4
#define UNROLL 8
#define BLOCK 256

typedef float vfloat4 __attribute__((ext_vector_type(4)));

__global__ __launch_bounds__(256) void IF_18622978195596_kernel(
    const vfloat4* __restrict__ x, const float* __restrict__ thresh_p,
    vfloat4* __restrict__ out, int n4) {
    // n4 = 2^21 divides exactly by BLOCK*UNROLL = 2048; no guards.
    const size_t base = (size_t)blockIdx.x * (BLOCK * UNROLL) + threadIdx.x;
    const float th = *thresh_p;

    vfloat4 xv[UNROLL][T_STEPS];

    // ---- load phase: plane-major. 8 consecutive 1KB wave-requests per
    // plane (8KB contiguous runs), then hop to the next 32-MiB plane. ----
#pragma unroll
    for (int t = 0; t < T_STEPS; ++t) {
#pragma unroll
        for (int u = 0; u < UNROLL; ++u) {
            const size_t i = base + (size_t)u * BLOCK;
            xv[u][t] = __builtin_nontemporal_load(&x[(size_t)t * n4 + i]);
        }
        __builtin_amdgcn_sched_barrier(0);  // pin plane grouping
    }

    // ---- compute phase: registers only; spike overwrites xv in place ----
#pragma unroll
    for (int u = 0; u < UNROLL; ++u) {
        vfloat4 mem = {0.5f * th, 0.5f * th, 0.5f * th, 0.5f * th};
#pragma unroll
        for (int t = 0; t < T_STEPS; ++t) {
            mem += xv[u][t];
            vfloat4 s;
            s.x = (mem.x >= th) ? th : 0.0f;
            s.y = (mem.y >= th) ? th : 0.0f;
            s.z = (mem.z >= th) ? th : 0.0f;
            s.w = (mem.w >= th) ? th : 0.0f;
            mem -= s;
            xv[u][t] = s;  // reuse the load registers for the store burst
        }
    }
    __builtin_amdgcn_sched_barrier(0);

    // ---- store phase: plane-major burst, same geometry as loads ----
#pragma unroll
    for (int t = 0; t < T_STEPS; ++t) {
#pragma unroll
        for (int u = 0; u < UNROLL; ++u) {
            const size_t i = base + (size_t)u * BLOCK;
            __builtin_nontemporal_store(xv[u][t], &out[(size_t)t * n4 + i]);
        }
        __builtin_amdgcn_sched_barrier(0);  // pin plane grouping
    }
}

extern "C" void kernel_launch(void* const* d_in, const int* in_sizes, int n_in,
                              void* d_out, int out_size, void* d_ws,
                              size_t ws_size, hipStream_t stream) {
    const float* x = (const float*)d_in[0];
    const float* thresh = (const float*)d_in[1];
    float* out = (float*)d_out;

    int total = in_sizes[0];        // 33,554,432 floats
    int n_per_t = total / T_STEPS;  // 8,388,608 neurons
    int n4 = n_per_t / 4;           // 2,097,152 vfloat4 per timestep

    int per_block = BLOCK * UNROLL;  // 2048 vfloat4 per block per t
    int grid = n4 / per_block;       // 1024 blocks
    IF_18622978195596_kernel<<<grid, BLOCK, 0, stream>>>(
        (const vfloat4*)x, thresh, (vfloat4*)out, n4);
}